// Round 4
// baseline (619.648 us; speedup 1.0000x reference)
//
#include <hip/hip_runtime.h>
#include <hip/hip_bf16.h>
#include <math.h>

// Profile-HMM forward (scaled). M=4, B=64, L=512, Q=512, S=26.
//
// Round 10 = round 9 + single-phase fused step (MFMA/VALU overlap):
//  - The old structure serialized {pack+sum | barrier | MFMA}: kc-outer MFMA
//    meant no acc completed until all 16 MFMAs done, so all post-VALU ran
//    with the matrix pipe idle (MfmaUtil+VALUBusy summed to ~100%).
//  - New body: barrier -> publish S_t, compute g_{t+1} (lag-2 gain known
//    BEFORE the MFMAs) -> load af -> per h-group {4-MFMA chain -> v=acc*e ->
//    pack g_{t+1}*v -> ds_write albuf[par^1] -> ps accum} -> ps publish ->
//    barrier. Legal because albuf is double-buffered (MFMA reads albuf[par],
//    pack writes albuf[par^1]) and lam is lag-2. Post-VALU of h-group i now
//    issues under the MFMA chains of groups i+1.. -> one phase per step.
//  - Numerically identical to round 9 (same gains, same pack values; only
//    the ps summation association differs, which only feeds the
//    self-correcting gain estimator; ll bookkeeping exact as before).

#define MM 4
#define BB 64
#define LL 512
#define QQ 512
#define SS 26
#define ASTR 528   // albuf row stride bytes (16-mult)

typedef float f32x4 __attribute__((ext_vector_type(4)));
typedef int i32x4 __attribute__((ext_vector_type(4)));
typedef int i32x8 __attribute__((ext_vector_type(8)));

__device__ __forceinline__ float bf2f(unsigned short u) {
    return __uint_as_float(((unsigned)u) << 16);
}
__device__ __forceinline__ unsigned short f2bf(float f) {
    unsigned u = __float_as_uint(f);
    u = u + 0x7FFFu + ((u >> 16) & 1u);   // RNE
    return (unsigned short)(u >> 16);
}
__device__ __forceinline__ unsigned char f2fp8(float x) {
    int r = __builtin_amdgcn_cvt_pk_fp8_f32(x, x, 0, false);
    return (unsigned char)(r & 0xFF);
}
__device__ __forceinline__ i32x8 ld32B(const unsigned char* p) {
    i32x4 lo = *(const i32x4*)p;
    i32x4 hi = *(const i32x4*)(p + 16);
    return __builtin_shufflevector(lo, hi, 0, 1, 2, 3, 4, 5, 6, 7);
}
// Barrier that waits only on LDS ops (no vmcnt drain).
// imm 0xC07F: vmcnt=63 (no wait), expcnt=7 (no wait), lgkmcnt=0 (full wait).
__device__ __forceinline__ void barrier_lds() {
    __asm__ __volatile__("" ::: "memory");
    __builtin_amdgcn_s_waitcnt(0xC07F);
    __builtin_amdgcn_s_barrier();
    __asm__ __volatile__("" ::: "memory");
}

// ---------------- preproc (unchanged) ----------------

__global__ void prep_small(const float* __restrict__ il, const float* __restrict__ em,
                           float* __restrict__ pi, float* __restrict__ Bem) {
    int blk = blockIdx.x;
    int m = blk / (QQ + 1);
    int r = blk % (QQ + 1);
    int lane = threadIdx.x;
    if (r < QQ) {
        float x = (lane < SS) ? em[((size_t)m * QQ + r) * SS + lane] : -1e30f;
        float mx = x;
        #pragma unroll
        for (int o = 1; o < 64; o <<= 1) mx = fmaxf(mx, __shfl_xor(mx, o));
        float e = (lane < SS) ? __expf(x - mx) : 0.f;
        float s = e;
        #pragma unroll
        for (int o = 1; o < 64; o <<= 1) s += __shfl_xor(s, o);
        if (lane < SS) Bem[((size_t)m * QQ + r) * SS + lane] = e / s;
    } else {
        float v[8];
        float mx = -1e30f;
        #pragma unroll
        for (int k = 0; k < 8; ++k) { v[k] = il[m * QQ + k * 64 + lane]; mx = fmaxf(mx, v[k]); }
        #pragma unroll
        for (int o = 1; o < 64; o <<= 1) mx = fmaxf(mx, __shfl_xor(mx, o));
        float s = 0.f;
        #pragma unroll
        for (int k = 0; k < 8; ++k) { v[k] = __expf(v[k] - mx); s += v[k]; }
        #pragma unroll
        for (int o = 1; o < 64; o <<= 1) s += __shfl_xor(s, o);
        #pragma unroll
        for (int k = 0; k < 8; ++k) pi[m * QQ + k * 64 + lane] = v[k] / s;
    }
}

__global__ void prep_arow(const float* __restrict__ Al, float* __restrict__ Lrow) {
    int row = blockIdx.x;
    int lane = threadIdx.x;
    const float* p = Al + (size_t)row * QQ;
    float v[8];
    float mx = -1e30f;
    #pragma unroll
    for (int k = 0; k < 8; ++k) { v[k] = p[k * 64 + lane]; mx = fmaxf(mx, v[k]); }
    #pragma unroll
    for (int o = 1; o < 64; o <<= 1) mx = fmaxf(mx, __shfl_xor(mx, o));
    float s = 0.f;
    #pragma unroll
    for (int k = 0; k < 8; ++k) s += __expf(v[k] - mx);
    #pragma unroll
    for (int o = 1; o < 64; o <<= 1) s += __shfl_xor(s, o);
    if (lane == 0) Lrow[row] = mx + __logf(s);
}

// Atq[m][p][q] = fp8(256 * softmax_over_p(A_logits[m][q][:])[p])  (natural q)
__global__ void prep_atq(const float* __restrict__ Al, const float* __restrict__ Lrow,
                         unsigned char* __restrict__ Atq) {
    int bid = blockIdx.x;
    int m = bid >> 3, pb = bid & 7;
    __shared__ unsigned char tile[64][68];
    int l6 = threadIdx.x & 63, g = threadIdx.x >> 6;
    for (int c = 0; c < 8; ++c) {
        #pragma unroll
        for (int r = 0; r < 16; ++r) {
            int ql = g * 16 + r;
            int q = c * 64 + ql;
            float x = Al[((size_t)m * QQ + q) * QQ + pb * 64 + l6];
            tile[ql][l6] = f2fp8(__expf(x - Lrow[m * QQ + q]) * 256.f);
        }
        __syncthreads();
        #pragma unroll
        for (int r = 0; r < 16; ++r) {
            int pr = g * 16 + r;
            Atq[((size_t)m * QQ + pb * 64 + pr) * QQ + c * 64 + l6] = tile[l6][pr];
        }
        __syncthreads();
    }
}

__global__ void prep_e(const float* __restrict__ inp, const float* __restrict__ Bem,
                       unsigned short* __restrict__ E) {
    int bid = blockIdx.x;
    int tc = bid & 7;
    int b = (bid >> 3) & 63;
    int m = bid >> 9;
    int q0 = threadIdx.x;
    float bem0[SS], bem1[SS];
    const float* bp = Bem + (size_t)m * QQ * SS;
    #pragma unroll
    for (int j = 0; j < SS; ++j) bem0[j] = bp[(size_t)q0 * SS + j];
    #pragma unroll
    for (int j = 0; j < SS; ++j) bem1[j] = bp[(size_t)(q0 + 256) * SS + j];
    const float* ip = inp + (((size_t)(m * BB + b)) * LL + tc * 64) * SS;
    for (int lt = 0; lt < 64; ++lt) {
        int t = tc * 64 + lt;
        float a0 = 0.f, a1 = 0.f;
        #pragma unroll
        for (int j = 0; j < SS; ++j) {
            float x = ip[lt * SS + j];
            a0 += x * bem0[j];
            a1 += x * bem1[j];
        }
        size_t o = (((size_t)m * LL + t) * BB + b) * QQ + q0;
        E[o] = f2bf(a0);
        E[o + 256] = f2bf(a1);
    }
}

// ---------------- scan ----------------

__launch_bounds__(512, 2)
__global__ void hmm_scan(const unsigned short* __restrict__ E,
                         const unsigned char* __restrict__ Atq,
                         const float* __restrict__ pi,
                         float* __restrict__ out) {
    const int c = blockIdx.x;               // 16 clusters
    const int m = c >> 2, bg = c & 3;
    const int tid = threadIdx.x;
    const int lane = tid & 63;
    const int wv = tid >> 6;                // 0..7, owns p = wv*64 .. wv*64+63
    const int sl = lane & 15;               // this lane's stream
    const int quad = lane >> 4;             // q-subchunk / MFMA k-group
    const float LOG256 = 5.545177444479562f;

    __shared__ unsigned char albuf[2][16 * ASTR];       // [parity][s][q] fp8
    __shared__ __align__(16) float psl[2][16][20];      // [parity][s][2*wave+half]
    __shared__ float Sfin[2][16];                       // [parity][s] published S_t

    // persistent fragments: this wave's 64 p-rows of fp8(256*A[m]) -> MFMA A-op.
    i32x8 breg[4][4];
    {
        const unsigned char* Ab = Atq + (size_t)m * QQ * QQ;
        #pragma unroll
        for (int h = 0; h < 4; ++h) {
            int p = wv * 64 + h * 16 + sl;
            const unsigned char* rp = Ab + (size_t)p * QQ + quad * 32;
            #pragma unroll
            for (int kc = 0; kc < 4; ++kc)
                breg[h][kc] = ld32B(rp + kc * 128);
        }
    }

    // albuf write offsets: row sl, b32 covering q = wv*64 + h*16 + quad*4 .. +3
    int wq[4];
    #pragma unroll
    for (int h = 0; h < 4; ++h)
        wq[h] = sl * ASTR + wv * 64 + h * 16 + quad * 4;

    const int b = bg * 16 + sl;
    const size_t ebase = (size_t)m * LL * BB * QQ;
    const ushort4* __restrict__ E4 = (const ushort4*)(E + ebase);
    const unsigned ESTR4 = (BB * QQ) >> 2;          // one time-row, ushort4 units
    const unsigned ebq = (unsigned)(b * QQ) >> 2;   // this stream's row base
    unsigned eoffs[4];
    #pragma unroll
    for (int h = 0; h < 4; ++h) eoffs[h] = (unsigned)(wv * 16 + h * 4 + quad);

    float v[4][4];
    ushort4 ea[4], eb[4];

    float gcur, gprev, ll;

    // prologue: v_0 = pi * e_0; pack alpha_0 with g_0 = 256; S_0 partials.
    {
        #pragma unroll
        for (int h = 0; h < 4; ++h) ea[h] = E4[ebq + ESTR4 + eoffs[h]];
        #pragma unroll
        for (int h = 0; h < 4; ++h) {
            int p0 = wv * 64 + h * 16 + quad * 4;
            f32x4 pv = *(const f32x4*)(pi + m * QQ + p0);
            ushort4 e0 = E4[ebq + eoffs[h]];
            v[h][0] = pv[0] * bf2f(e0.x);
            v[h][1] = pv[1] * bf2f(e0.y);
            v[h][2] = pv[2] * bf2f(e0.z);
            v[h][3] = pv[3] * bf2f(e0.w);
        }
        gcur = 256.f;       // g_0 = 128 / lam_0, lam_0 = 0.5
        gprev = 1.0f;
        unsigned char* ab = &albuf[0][0];
        #pragma unroll
        for (int h = 0; h < 4; ++h) {
            int d = __builtin_amdgcn_cvt_pk_fp8_f32(gcur * v[h][0], gcur * v[h][1], 0, false);
            d = __builtin_amdgcn_cvt_pk_fp8_f32(gcur * v[h][2], gcur * v[h][3], d, true);
            *(int*)(ab + wq[h]) = d;
        }
        float ps = ((v[0][0] + v[0][1]) + (v[0][2] + v[0][3]))
                 + ((v[1][0] + v[1][1]) + (v[1][2] + v[1][3]))
                 + ((v[2][0] + v[2][1]) + (v[2][2] + v[2][3]))
                 + ((v[3][0] + v[3][1]) + (v[3][2] + v[3][3]));
        ps += __shfl_xor(ps, 16);
        if ((quad & 1) == 0) psl[0][sl][2 * wv + (quad >> 1)] = ps;
        ll = -(__logf(gcur) + LOG256);
        barrier_lds();
    }

    // single-phase body: at entry albuf[par] = alpha-hat_t, psl[par] = S_t
    // partials, Sfin[par^1] = S_{t-1}. Produces v_{t+1}, packs alpha_{t+1}
    // into albuf[par^1] fused with the MFMA h-loop.
    auto body = [&](int par, bool first, ushort4 (&ecur)[4], ushort4 (&enxt)[4],
                    unsigned epre) {
        // prefetch e_{t+2} (consumed next body; never force-drained)
        #pragma unroll
        for (int h = 0; h < 4; ++h) enxt[h] = E4[epre + eoffs[h]];

        // wave 0 publishes S_t (consumed by body t+1's gain update)
        if (wv == 0 && lane < 16) {
            const f32x4* pr = (const f32x4*)&psl[par][lane][0];
            f32x4 ss4 = (pr[0] + pr[1]) + (pr[2] + pr[3]);
            Sfin[par][lane] = (ss4[0] + ss4[1]) + (ss4[2] + ss4[3]);
        }
        // lag-2 gain for alpha_{t+1}: known BEFORE the MFMAs.
        float lam = first ? 16384.0f
                          : 16384.0f * gcur * gprev * Sfin[par ^ 1][sl];
        float gnext = 128.0f * __builtin_amdgcn_rcpf(lam);

        // B-operand chunks for this lane's stream (albuf[par])
        const unsigned char* ar = &albuf[par][0] + sl * ASTR + quad * 32;
        i32x8 af0 = ld32B(ar);
        i32x8 af1 = ld32B(ar + 128);
        i32x8 af2 = ld32B(ar + 256);
        i32x8 af3 = ld32B(ar + 384);

        unsigned char* ab = &albuf[par ^ 1][0];
        float ps = 0.f;
        #pragma unroll
        for (int h = 0; h < 4; ++h) {
            f32x4 acc = (f32x4){0.f, 0.f, 0.f, 0.f};
            acc = __builtin_amdgcn_mfma_scale_f32_16x16x128_f8f6f4(
                breg[h][0], af0, acc, 0, 0, 0, 0x7F7F7F7F, 0, 0x7F7F7F7F);
            acc = __builtin_amdgcn_mfma_scale_f32_16x16x128_f8f6f4(
                breg[h][1], af1, acc, 0, 0, 0, 0x7F7F7F7F, 0, 0x7F7F7F7F);
            acc = __builtin_amdgcn_mfma_scale_f32_16x16x128_f8f6f4(
                breg[h][2], af2, acc, 0, 0, 0, 0x7F7F7F7F, 0, 0x7F7F7F7F);
            acc = __builtin_amdgcn_mfma_scale_f32_16x16x128_f8f6f4(
                breg[h][3], af3, acc, 0, 0, 0, 0x7F7F7F7F, 0, 0x7F7F7F7F);
            // fused post: issues under the MFMA chains of later h-groups
            v[h][0] = acc[0] * bf2f(ecur[h].x);
            v[h][1] = acc[1] * bf2f(ecur[h].y);
            v[h][2] = acc[2] * bf2f(ecur[h].z);
            v[h][3] = acc[3] * bf2f(ecur[h].w);
            int d = __builtin_amdgcn_cvt_pk_fp8_f32(gnext * v[h][0], gnext * v[h][1], 0, false);
            d = __builtin_amdgcn_cvt_pk_fp8_f32(gnext * v[h][2], gnext * v[h][3], d, true);
            *(int*)(ab + wq[h]) = d;
            ps += (v[h][0] + v[h][1]) + (v[h][2] + v[h][3]);
        }
        ps += __shfl_xor(ps, 16);
        if ((quad & 1) == 0) psl[par ^ 1][sl][2 * wv + (quad >> 1)] = ps;
        ll -= __logf(gnext) + LOG256;   // exact bookkeeping for alpha_{t+1}
        gprev = gcur; gcur = gnext;
        barrier_lds();                  // LDS-only wait; no vmcnt drain
    };

    // bodies t = 0..509 (510 of them), then final transition without pack.
    unsigned epre = ebq + 2 * ESTR4;
    body(0, true,  ea, eb, epre); epre += ESTR4;
    body(1, false, eb, ea, epre); epre += ESTR4;
    for (int t = 2; t < LL - 2; t += 2) {
        body(0, false, ea, eb, epre); epre += ESTR4;
        body(1, false, eb, ea, epre); epre += ESTR4;
    }
    // final transition (t = 510): v_511 only; no pack / ll / psl.
    {
        const unsigned char* ar = &albuf[0][0] + sl * ASTR + quad * 32;
        i32x8 af0 = ld32B(ar);
        i32x8 af1 = ld32B(ar + 128);
        i32x8 af2 = ld32B(ar + 256);
        i32x8 af3 = ld32B(ar + 384);
        #pragma unroll
        for (int h = 0; h < 4; ++h) {
            f32x4 acc = (f32x4){0.f, 0.f, 0.f, 0.f};
            acc = __builtin_amdgcn_mfma_scale_f32_16x16x128_f8f6f4(
                breg[h][0], af0, acc, 0, 0, 0, 0x7F7F7F7F, 0, 0x7F7F7F7F);
            acc = __builtin_amdgcn_mfma_scale_f32_16x16x128_f8f6f4(
                breg[h][1], af1, acc, 0, 0, 0, 0x7F7F7F7F, 0, 0x7F7F7F7F);
            acc = __builtin_amdgcn_mfma_scale_f32_16x16x128_f8f6f4(
                breg[h][2], af2, acc, 0, 0, 0, 0x7F7F7F7F, 0, 0x7F7F7F7F);
            acc = __builtin_amdgcn_mfma_scale_f32_16x16x128_f8f6f4(
                breg[h][3], af3, acc, 0, 0, 0, 0x7F7F7F7F, 0, 0x7F7F7F7F);
            v[h][0] = acc[0] * bf2f(ea[h].x);
            v[h][1] = acc[1] * bf2f(ea[h].y);
            v[h][2] = acc[2] * bf2f(ea[h].z);
            v[h][3] = acc[3] * bf2f(ea[h].w);
        }
    }

    // epilogue: exact S_511 (full reduction; one heavyweight barrier is fine)
    {
        float ps = ((v[0][0] + v[0][1]) + (v[0][2] + v[0][3]))
                 + ((v[1][0] + v[1][1]) + (v[1][2] + v[1][3]))
                 + ((v[2][0] + v[2][1]) + (v[2][2] + v[2][3]))
                 + ((v[3][0] + v[3][1]) + (v[3][2] + v[3][3]));
        ps += __shfl_xor(ps, 16);
        if ((quad & 1) == 0) psl[1][sl][2 * wv + (quad >> 1)] = ps;
        __syncthreads();
        if (wv == 0 && lane < 16) {
            const f32x4* pr = (const f32x4*)&psl[1][lane][0];
            f32x4 ss4 = (pr[0] + pr[1]) + (pr[2] + pr[3]);
            float S = (ss4[0] + ss4[1]) + (ss4[2] + ss4[3]);
            out[m * BB + bg * 16 + lane] = ll + __logf(S);
        }
    }
}

// ---------------- host ----------------

extern "C" void kernel_launch(void* const* d_in, const int* in_sizes, int n_in,
                              void* d_out, int out_size, void* d_ws, size_t ws_size,
                              hipStream_t stream) {
    const float* inputs = (const float*)d_in[0];
    const float* A_logits = (const float*)d_in[1];
    const float* init_logits = (const float*)d_in[2];
    const float* em_logits = (const float*)d_in[3];
    float* out = (float*)d_out;

    char* ws = (char*)d_ws;
    size_t off = 0;
    unsigned short* E = (unsigned short*)(ws + off);  off += (size_t)MM * LL * BB * QQ * 2;  // 134 MB
    unsigned char* Atq = (unsigned char*)(ws + off);  off += (size_t)MM * QQ * QQ;           // 1 MB
    float* Bem = (float*)(ws + off);                  off += (size_t)MM * QQ * SS * 4;
    float* pi = (float*)(ws + off);                   off += (size_t)MM * QQ * 4;
    float* Lrow = (float*)(ws + off);                 off += (size_t)MM * QQ * 4;

    if (ws_size < off) {
        (void)hipMemsetAsync(d_out, 0, (size_t)out_size * sizeof(float), stream);
        return;
    }

    prep_small<<<dim3(MM * (QQ + 1)), dim3(64), 0, stream>>>(init_logits, em_logits, pi, Bem);
    prep_arow<<<dim3(MM * QQ), dim3(64), 0, stream>>>(A_logits, Lrow);
    prep_atq<<<dim3(MM * 8), dim3(256), 0, stream>>>(A_logits, Lrow, Atq);
    prep_e<<<dim3(MM * BB * 8), dim3(256), 0, stream>>>(inputs, Bem, E);
    hmm_scan<<<dim3(16), dim3(512), 0, stream>>>(E, Atq, pi, out);
}

// Round 5
// 597.164 us; speedup vs baseline: 1.0377x; 1.0377x over previous
//
#include <hip/hip_runtime.h>
#include <hip/hip_bf16.h>
#include <math.h>

// Profile-HMM forward (scaled). M=4, B=64, L=512, Q=512, S=26.
//
// Round 11 = round 9 skeleton + CORRECT MFMA/VALU overlap (fixing round 10):
//  - R10's failure: h-outer MFMA chains = 4 dependent MFMAs at spacing 1 ->
//    dep-latency stalls (both MfmaUtil and VALUBusy dropped). R9's kc-outer
//    order had no dep stalls but ALL accs completed in the last 4 MFMAs, so
//    the entire post-VALU phase ran with the matrix pipe drained.
//  - New order per body: A-half = (h0,kc0)(h1,kc0)(h0,kc1)...(h1,kc3)
//    [spacing-2 chains], then B-half (h2,h3) ISSUED BEFORE post-A. post-A
//    (v=acc*e, pack, ds_write for h0,h1) executes while the B-half MFMAs
//    (~550 pipe-cyc/SIMD for 2 waves) drain; only post-B's short tail sits
//    outside the pipe shadow. MFMA issue is non-blocking, so each wave's
//    post-A dual-flows in the issue gaps.
//  - Everything else identical to round 10 (lag-2 gain known before MFMAs,
//    double-buffered albuf, one LDS-only barrier per step, strength-reduced
//    e-prefetch). Numerics identical.

#define MM 4
#define BB 64
#define LL 512
#define QQ 512
#define SS 26
#define ASTR 528   // albuf row stride bytes (16-mult)

typedef float f32x4 __attribute__((ext_vector_type(4)));
typedef int i32x4 __attribute__((ext_vector_type(4)));
typedef int i32x8 __attribute__((ext_vector_type(8)));

__device__ __forceinline__ float bf2f(unsigned short u) {
    return __uint_as_float(((unsigned)u) << 16);
}
__device__ __forceinline__ unsigned short f2bf(float f) {
    unsigned u = __float_as_uint(f);
    u = u + 0x7FFFu + ((u >> 16) & 1u);   // RNE
    return (unsigned short)(u >> 16);
}
__device__ __forceinline__ unsigned char f2fp8(float x) {
    int r = __builtin_amdgcn_cvt_pk_fp8_f32(x, x, 0, false);
    return (unsigned char)(r & 0xFF);
}
__device__ __forceinline__ i32x8 ld32B(const unsigned char* p) {
    i32x4 lo = *(const i32x4*)p;
    i32x4 hi = *(const i32x4*)(p + 16);
    return __builtin_shufflevector(lo, hi, 0, 1, 2, 3, 4, 5, 6, 7);
}
#define MFMA8(A, B, C) __builtin_amdgcn_mfma_scale_f32_16x16x128_f8f6f4( \
    (A), (B), (C), 0, 0, 0, 0x7F7F7F7F, 0, 0x7F7F7F7F)
// Barrier that waits only on LDS ops (no vmcnt drain).
// imm 0xC07F: vmcnt=63 (no wait), expcnt=7 (no wait), lgkmcnt=0 (full wait).
__device__ __forceinline__ void barrier_lds() {
    __asm__ __volatile__("" ::: "memory");
    __builtin_amdgcn_s_waitcnt(0xC07F);
    __builtin_amdgcn_s_barrier();
    __asm__ __volatile__("" ::: "memory");
}

// ---------------- preproc (unchanged) ----------------

__global__ void prep_small(const float* __restrict__ il, const float* __restrict__ em,
                           float* __restrict__ pi, float* __restrict__ Bem) {
    int blk = blockIdx.x;
    int m = blk / (QQ + 1);
    int r = blk % (QQ + 1);
    int lane = threadIdx.x;
    if (r < QQ) {
        float x = (lane < SS) ? em[((size_t)m * QQ + r) * SS + lane] : -1e30f;
        float mx = x;
        #pragma unroll
        for (int o = 1; o < 64; o <<= 1) mx = fmaxf(mx, __shfl_xor(mx, o));
        float e = (lane < SS) ? __expf(x - mx) : 0.f;
        float s = e;
        #pragma unroll
        for (int o = 1; o < 64; o <<= 1) s += __shfl_xor(s, o);
        if (lane < SS) Bem[((size_t)m * QQ + r) * SS + lane] = e / s;
    } else {
        float v[8];
        float mx = -1e30f;
        #pragma unroll
        for (int k = 0; k < 8; ++k) { v[k] = il[m * QQ + k * 64 + lane]; mx = fmaxf(mx, v[k]); }
        #pragma unroll
        for (int o = 1; o < 64; o <<= 1) mx = fmaxf(mx, __shfl_xor(mx, o));
        float s = 0.f;
        #pragma unroll
        for (int k = 0; k < 8; ++k) { v[k] = __expf(v[k] - mx); s += v[k]; }
        #pragma unroll
        for (int o = 1; o < 64; o <<= 1) s += __shfl_xor(s, o);
        #pragma unroll
        for (int k = 0; k < 8; ++k) pi[m * QQ + k * 64 + lane] = v[k] / s;
    }
}

__global__ void prep_arow(const float* __restrict__ Al, float* __restrict__ Lrow) {
    int row = blockIdx.x;
    int lane = threadIdx.x;
    const float* p = Al + (size_t)row * QQ;
    float v[8];
    float mx = -1e30f;
    #pragma unroll
    for (int k = 0; k < 8; ++k) { v[k] = p[k * 64 + lane]; mx = fmaxf(mx, v[k]); }
    #pragma unroll
    for (int o = 1; o < 64; o <<= 1) mx = fmaxf(mx, __shfl_xor(mx, o));
    float s = 0.f;
    #pragma unroll
    for (int k = 0; k < 8; ++k) s += __expf(v[k] - mx);
    #pragma unroll
    for (int o = 1; o < 64; o <<= 1) s += __shfl_xor(s, o);
    if (lane == 0) Lrow[row] = mx + __logf(s);
}

// Atq[m][p][q] = fp8(256 * softmax_over_p(A_logits[m][q][:])[p])  (natural q)
__global__ void prep_atq(const float* __restrict__ Al, const float* __restrict__ Lrow,
                         unsigned char* __restrict__ Atq) {
    int bid = blockIdx.x;
    int m = bid >> 3, pb = bid & 7;
    __shared__ unsigned char tile[64][68];
    int l6 = threadIdx.x & 63, g = threadIdx.x >> 6;
    for (int c = 0; c < 8; ++c) {
        #pragma unroll
        for (int r = 0; r < 16; ++r) {
            int ql = g * 16 + r;
            int q = c * 64 + ql;
            float x = Al[((size_t)m * QQ + q) * QQ + pb * 64 + l6];
            tile[ql][l6] = f2fp8(__expf(x - Lrow[m * QQ + q]) * 256.f);
        }
        __syncthreads();
        #pragma unroll
        for (int r = 0; r < 16; ++r) {
            int pr = g * 16 + r;
            Atq[((size_t)m * QQ + pb * 64 + pr) * QQ + c * 64 + l6] = tile[l6][pr];
        }
        __syncthreads();
    }
}

__global__ void prep_e(const float* __restrict__ inp, const float* __restrict__ Bem,
                       unsigned short* __restrict__ E) {
    int bid = blockIdx.x;
    int tc = bid & 7;
    int b = (bid >> 3) & 63;
    int m = bid >> 9;
    int q0 = threadIdx.x;
    float bem0[SS], bem1[SS];
    const float* bp = Bem + (size_t)m * QQ * SS;
    #pragma unroll
    for (int j = 0; j < SS; ++j) bem0[j] = bp[(size_t)q0 * SS + j];
    #pragma unroll
    for (int j = 0; j < SS; ++j) bem1[j] = bp[(size_t)(q0 + 256) * SS + j];
    const float* ip = inp + (((size_t)(m * BB + b)) * LL + tc * 64) * SS;
    for (int lt = 0; lt < 64; ++lt) {
        int t = tc * 64 + lt;
        float a0 = 0.f, a1 = 0.f;
        #pragma unroll
        for (int j = 0; j < SS; ++j) {
            float x = ip[lt * SS + j];
            a0 += x * bem0[j];
            a1 += x * bem1[j];
        }
        size_t o = (((size_t)m * LL + t) * BB + b) * QQ + q0;
        E[o] = f2bf(a0);
        E[o + 256] = f2bf(a1);
    }
}

// ---------------- scan ----------------

__launch_bounds__(512, 2)
__global__ void hmm_scan(const unsigned short* __restrict__ E,
                         const unsigned char* __restrict__ Atq,
                         const float* __restrict__ pi,
                         float* __restrict__ out) {
    const int c = blockIdx.x;               // 16 clusters
    const int m = c >> 2, bg = c & 3;
    const int tid = threadIdx.x;
    const int lane = tid & 63;
    const int wv = tid >> 6;                // 0..7, owns p = wv*64 .. wv*64+63
    const int sl = lane & 15;               // this lane's stream
    const int quad = lane >> 4;             // q-subchunk / MFMA k-group
    const float LOG256 = 5.545177444479562f;

    __shared__ unsigned char albuf[2][16 * ASTR];       // [parity][s][q] fp8
    __shared__ __align__(16) float psl[2][16][20];      // [parity][s][2*wave+half]
    __shared__ float Sfin[2][16];                       // [parity][s] published S_t

    // persistent fragments: this wave's 64 p-rows of fp8(256*A[m]) -> MFMA A-op.
    i32x8 breg[4][4];
    {
        const unsigned char* Ab = Atq + (size_t)m * QQ * QQ;
        #pragma unroll
        for (int h = 0; h < 4; ++h) {
            int p = wv * 64 + h * 16 + sl;
            const unsigned char* rp = Ab + (size_t)p * QQ + quad * 32;
            #pragma unroll
            for (int kc = 0; kc < 4; ++kc)
                breg[h][kc] = ld32B(rp + kc * 128);
        }
    }

    // albuf write offsets: row sl, b32 covering q = wv*64 + h*16 + quad*4 .. +3
    int wq[4];
    #pragma unroll
    for (int h = 0; h < 4; ++h)
        wq[h] = sl * ASTR + wv * 64 + h * 16 + quad * 4;

    const int b = bg * 16 + sl;
    const size_t ebase = (size_t)m * LL * BB * QQ;
    const ushort4* __restrict__ E4 = (const ushort4*)(E + ebase);
    const unsigned ESTR4 = (BB * QQ) >> 2;          // one time-row, ushort4 units
    const unsigned ebq = (unsigned)(b * QQ) >> 2;   // this stream's row base
    unsigned eoffs[4];
    #pragma unroll
    for (int h = 0; h < 4; ++h) eoffs[h] = (unsigned)(wv * 16 + h * 4 + quad);

    float v[4][4];
    ushort4 ea[4], eb[4];

    float gcur, gprev, ll;

    // prologue: v_0 = pi * e_0; pack alpha_0 with g_0 = 256; S_0 partials.
    {
        #pragma unroll
        for (int h = 0; h < 4; ++h) ea[h] = E4[ebq + ESTR4 + eoffs[h]];
        #pragma unroll
        for (int h = 0; h < 4; ++h) {
            int p0 = wv * 64 + h * 16 + quad * 4;
            f32x4 pv = *(const f32x4*)(pi + m * QQ + p0);
            ushort4 e0 = E4[ebq + eoffs[h]];
            v[h][0] = pv[0] * bf2f(e0.x);
            v[h][1] = pv[1] * bf2f(e0.y);
            v[h][2] = pv[2] * bf2f(e0.z);
            v[h][3] = pv[3] * bf2f(e0.w);
        }
        gcur = 256.f;       // g_0 = 128 / lam_0, lam_0 = 0.5
        gprev = 1.0f;
        unsigned char* ab = &albuf[0][0];
        #pragma unroll
        for (int h = 0; h < 4; ++h) {
            int d = __builtin_amdgcn_cvt_pk_fp8_f32(gcur * v[h][0], gcur * v[h][1], 0, false);
            d = __builtin_amdgcn_cvt_pk_fp8_f32(gcur * v[h][2], gcur * v[h][3], d, true);
            *(int*)(ab + wq[h]) = d;
        }
        float ps = ((v[0][0] + v[0][1]) + (v[0][2] + v[0][3]))
                 + ((v[1][0] + v[1][1]) + (v[1][2] + v[1][3]))
                 + ((v[2][0] + v[2][1]) + (v[2][2] + v[2][3]))
                 + ((v[3][0] + v[3][1]) + (v[3][2] + v[3][3]));
        ps += __shfl_xor(ps, 16);
        if ((quad & 1) == 0) psl[0][sl][2 * wv + (quad >> 1)] = ps;
        ll = -(__logf(gcur) + LOG256);
        barrier_lds();
    }

    // body: at entry albuf[par] = alpha-hat_t, psl[par] = S_t partials,
    // Sfin[par^1] = S_{t-1}. Issues all 16 MFMAs in two spacing-2 halves,
    // then post-A (h0,h1) under the B-half's pipe time, then post-B.
    auto body = [&](int par, bool first, ushort4 (&ecur)[4], ushort4 (&enxt)[4],
                    unsigned epre) {
        // prefetch e_{t+2} (consumed next body; never force-drained)
        #pragma unroll
        for (int h = 0; h < 4; ++h) enxt[h] = E4[epre + eoffs[h]];

        // wave 0 publishes S_t (consumed by body t+1's gain update)
        if (wv == 0 && lane < 16) {
            const f32x4* pr = (const f32x4*)&psl[par][lane][0];
            f32x4 ss4 = (pr[0] + pr[1]) + (pr[2] + pr[3]);
            Sfin[par][lane] = (ss4[0] + ss4[1]) + (ss4[2] + ss4[3]);
        }
        // lag-2 gain for alpha_{t+1}: known BEFORE the MFMAs.
        float lam = first ? 16384.0f
                          : 16384.0f * gcur * gprev * Sfin[par ^ 1][sl];
        float gnext = 128.0f * __builtin_amdgcn_rcpf(lam);

        // B-operand chunks for this lane's stream (albuf[par])
        const unsigned char* ar = &albuf[par][0] + sl * ASTR + quad * 32;
        i32x8 af0 = ld32B(ar);
        i32x8 af1 = ld32B(ar + 128);
        i32x8 af2 = ld32B(ar + 256);
        i32x8 af3 = ld32B(ar + 384);

        // --- A-half: h0,h1 interleaved (dep spacing 2) ---
        f32x4 a0 = (f32x4){0.f, 0.f, 0.f, 0.f};
        f32x4 a1 = (f32x4){0.f, 0.f, 0.f, 0.f};
        a0 = MFMA8(breg[0][0], af0, a0);  a1 = MFMA8(breg[1][0], af0, a1);
        a0 = MFMA8(breg[0][1], af1, a0);  a1 = MFMA8(breg[1][1], af1, a1);
        a0 = MFMA8(breg[0][2], af2, a0);  a1 = MFMA8(breg[1][2], af2, a1);
        a0 = MFMA8(breg[0][3], af3, a0);  a1 = MFMA8(breg[1][3], af3, a1);
        // --- B-half issued before post-A: pipe stays fed during post-A ---
        f32x4 a2 = (f32x4){0.f, 0.f, 0.f, 0.f};
        f32x4 a3 = (f32x4){0.f, 0.f, 0.f, 0.f};
        a2 = MFMA8(breg[2][0], af0, a2);  a3 = MFMA8(breg[3][0], af0, a3);
        a2 = MFMA8(breg[2][1], af1, a2);  a3 = MFMA8(breg[3][1], af1, a3);
        a2 = MFMA8(breg[2][2], af2, a2);  a3 = MFMA8(breg[3][2], af2, a3);
        a2 = MFMA8(breg[2][3], af3, a2);  a3 = MFMA8(breg[3][3], af3, a3);

        // --- post-A: depends only on a0,a1; overlaps B-half pipe time ---
        unsigned char* ab = &albuf[par ^ 1][0];
        v[0][0] = a0[0] * bf2f(ecur[0].x);
        v[0][1] = a0[1] * bf2f(ecur[0].y);
        v[0][2] = a0[2] * bf2f(ecur[0].z);
        v[0][3] = a0[3] * bf2f(ecur[0].w);
        v[1][0] = a1[0] * bf2f(ecur[1].x);
        v[1][1] = a1[1] * bf2f(ecur[1].y);
        v[1][2] = a1[2] * bf2f(ecur[1].z);
        v[1][3] = a1[3] * bf2f(ecur[1].w);
        {
            int d0 = __builtin_amdgcn_cvt_pk_fp8_f32(gnext * v[0][0], gnext * v[0][1], 0, false);
            d0 = __builtin_amdgcn_cvt_pk_fp8_f32(gnext * v[0][2], gnext * v[0][3], d0, true);
            *(int*)(ab + wq[0]) = d0;
            int d1 = __builtin_amdgcn_cvt_pk_fp8_f32(gnext * v[1][0], gnext * v[1][1], 0, false);
            d1 = __builtin_amdgcn_cvt_pk_fp8_f32(gnext * v[1][2], gnext * v[1][3], d1, true);
            *(int*)(ab + wq[1]) = d1;
        }
        float psA = ((v[0][0] + v[0][1]) + (v[0][2] + v[0][3]))
                  + ((v[1][0] + v[1][1]) + (v[1][2] + v[1][3]));

        // --- post-B ---
        v[2][0] = a2[0] * bf2f(ecur[2].x);
        v[2][1] = a2[1] * bf2f(ecur[2].y);
        v[2][2] = a2[2] * bf2f(ecur[2].z);
        v[2][3] = a2[3] * bf2f(ecur[2].w);
        v[3][0] = a3[0] * bf2f(ecur[3].x);
        v[3][1] = a3[1] * bf2f(ecur[3].y);
        v[3][2] = a3[2] * bf2f(ecur[3].z);
        v[3][3] = a3[3] * bf2f(ecur[3].w);
        {
            int d2 = __builtin_amdgcn_cvt_pk_fp8_f32(gnext * v[2][0], gnext * v[2][1], 0, false);
            d2 = __builtin_amdgcn_cvt_pk_fp8_f32(gnext * v[2][2], gnext * v[2][3], d2, true);
            *(int*)(ab + wq[2]) = d2;
            int d3 = __builtin_amdgcn_cvt_pk_fp8_f32(gnext * v[3][0], gnext * v[3][1], 0, false);
            d3 = __builtin_amdgcn_cvt_pk_fp8_f32(gnext * v[3][2], gnext * v[3][3], d3, true);
            *(int*)(ab + wq[3]) = d3;
        }
        float ps = psA
                 + ((v[2][0] + v[2][1]) + (v[2][2] + v[2][3]))
                 + ((v[3][0] + v[3][1]) + (v[3][2] + v[3][3]));
        ps += __shfl_xor(ps, 16);
        if ((quad & 1) == 0) psl[par ^ 1][sl][2 * wv + (quad >> 1)] = ps;
        ll -= __logf(gnext) + LOG256;   // exact bookkeeping for alpha_{t+1}
        gprev = gcur; gcur = gnext;
        barrier_lds();                  // LDS-only wait; no vmcnt drain
    };

    // bodies t = 0..509 (510 of them), then final transition without pack.
    unsigned epre = ebq + 2 * ESTR4;
    body(0, true,  ea, eb, epre); epre += ESTR4;
    body(1, false, eb, ea, epre); epre += ESTR4;
    for (int t = 2; t < LL - 2; t += 2) {
        body(0, false, ea, eb, epre); epre += ESTR4;
        body(1, false, eb, ea, epre); epre += ESTR4;
    }
    // final transition (t = 510): v_511 only; no pack / ll / psl.
    {
        const unsigned char* ar = &albuf[0][0] + sl * ASTR + quad * 32;
        i32x8 af0 = ld32B(ar);
        i32x8 af1 = ld32B(ar + 128);
        i32x8 af2 = ld32B(ar + 256);
        i32x8 af3 = ld32B(ar + 384);
        f32x4 a0 = (f32x4){0.f, 0.f, 0.f, 0.f};
        f32x4 a1 = (f32x4){0.f, 0.f, 0.f, 0.f};
        f32x4 a2 = (f32x4){0.f, 0.f, 0.f, 0.f};
        f32x4 a3 = (f32x4){0.f, 0.f, 0.f, 0.f};
        a0 = MFMA8(breg[0][0], af0, a0);  a1 = MFMA8(breg[1][0], af0, a1);
        a2 = MFMA8(breg[2][0], af0, a2);  a3 = MFMA8(breg[3][0], af0, a3);
        a0 = MFMA8(breg[0][1], af1, a0);  a1 = MFMA8(breg[1][1], af1, a1);
        a2 = MFMA8(breg[2][1], af1, a2);  a3 = MFMA8(breg[3][1], af1, a3);
        a0 = MFMA8(breg[0][2], af2, a0);  a1 = MFMA8(breg[1][2], af2, a1);
        a2 = MFMA8(breg[2][2], af2, a2);  a3 = MFMA8(breg[3][2], af2, a3);
        a0 = MFMA8(breg[0][3], af3, a0);  a1 = MFMA8(breg[1][3], af3, a1);
        a2 = MFMA8(breg[2][3], af3, a2);  a3 = MFMA8(breg[3][3], af3, a3);
        v[0][0] = a0[0] * bf2f(ea[0].x);
        v[0][1] = a0[1] * bf2f(ea[0].y);
        v[0][2] = a0[2] * bf2f(ea[0].z);
        v[0][3] = a0[3] * bf2f(ea[0].w);
        v[1][0] = a1[0] * bf2f(ea[1].x);
        v[1][1] = a1[1] * bf2f(ea[1].y);
        v[1][2] = a1[2] * bf2f(ea[1].z);
        v[1][3] = a1[3] * bf2f(ea[1].w);
        v[2][0] = a2[0] * bf2f(ea[2].x);
        v[2][1] = a2[1] * bf2f(ea[2].y);
        v[2][2] = a2[2] * bf2f(ea[2].z);
        v[2][3] = a2[3] * bf2f(ea[2].w);
        v[3][0] = a3[0] * bf2f(ea[3].x);
        v[3][1] = a3[1] * bf2f(ea[3].y);
        v[3][2] = a3[2] * bf2f(ea[3].z);
        v[3][3] = a3[3] * bf2f(ea[3].w);
    }

    // epilogue: exact S_511 (full reduction; one heavyweight barrier is fine)
    {
        float ps = ((v[0][0] + v[0][1]) + (v[0][2] + v[0][3]))
                 + ((v[1][0] + v[1][1]) + (v[1][2] + v[1][3]))
                 + ((v[2][0] + v[2][1]) + (v[2][2] + v[2][3]))
                 + ((v[3][0] + v[3][1]) + (v[3][2] + v[3][3]));
        ps += __shfl_xor(ps, 16);
        if ((quad & 1) == 0) psl[1][sl][2 * wv + (quad >> 1)] = ps;
        __syncthreads();
        if (wv == 0 && lane < 16) {
            const f32x4* pr = (const f32x4*)&psl[1][lane][0];
            f32x4 ss4 = (pr[0] + pr[1]) + (pr[2] + pr[3]);
            float S = (ss4[0] + ss4[1]) + (ss4[2] + ss4[3]);
            out[m * BB + bg * 16 + lane] = ll + __logf(S);
        }
    }
}

// ---------------- host ----------------

extern "C" void kernel_launch(void* const* d_in, const int* in_sizes, int n_in,
                              void* d_out, int out_size, void* d_ws, size_t ws_size,
                              hipStream_t stream) {
    const float* inputs = (const float*)d_in[0];
    const float* A_logits = (const float*)d_in[1];
    const float* init_logits = (const float*)d_in[2];
    const float* em_logits = (const float*)d_in[3];
    float* out = (float*)d_out;

    char* ws = (char*)d_ws;
    size_t off = 0;
    unsigned short* E = (unsigned short*)(ws + off);  off += (size_t)MM * LL * BB * QQ * 2;  // 134 MB
    unsigned char* Atq = (unsigned char*)(ws + off);  off += (size_t)MM * QQ * QQ;           // 1 MB
    float* Bem = (float*)(ws + off);                  off += (size_t)MM * QQ * SS * 4;
    float* pi = (float*)(ws + off);                   off += (size_t)MM * QQ * 4;
    float* Lrow = (float*)(ws + off);                 off += (size_t)MM * QQ * 4;

    if (ws_size < off) {
        (void)hipMemsetAsync(d_out, 0, (size_t)out_size * sizeof(float), stream);
        return;
    }

    prep_small<<<dim3(MM * (QQ + 1)), dim3(64), 0, stream>>>(init_logits, em_logits, pi, Bem);
    prep_arow<<<dim3(MM * QQ), dim3(64), 0, stream>>>(A_logits, Lrow);
    prep_atq<<<dim3(MM * 8), dim3(256), 0, stream>>>(A_logits, Lrow, Atq);
    prep_e<<<dim3(MM * BB * 8), dim3(256), 0, stream>>>(inputs, Bem, E);
    hmm_scan<<<dim3(16), dim3(512), 0, stream>>>(E, Atq, pi, out);
}